// Round 17
// baseline (493.009 us; speedup 1.0000x reference)
//
#include <hip/hip_runtime.h>
#include <hip/hip_bf16.h>

#define BB 64
#define SS 512
#define II 32
#define HH 64
#define DD 128
#define FF 256
#define NHEAD 8
#define HDIM 16
#define NTOK (SS*BB)   // 32768

typedef short bf16x8 __attribute__((ext_vector_type(8)));
typedef float f32x4  __attribute__((ext_vector_type(4)));

__device__ __forceinline__ float fast_tanh(float x) {
    float ax = fabsf(x);
    float e = __expf(-2.0f * ax);
    float r = (1.0f - e) * __builtin_amdgcn_rcpf(1.0f + e);
    return copysignf(r, x);
}

__device__ __forceinline__ float bcast(float v, int lane) {
    return __int_as_float(__builtin_amdgcn_readlane(__float_as_int(v), lane));
}

// fp32 -> bf16 bits, round-to-nearest-even
__device__ __forceinline__ short f2bf(float x) {
    unsigned u = __float_as_uint(x);
    return (short)((u + 0x7FFFu + ((u >> 16) & 1u)) >> 16);
}
__device__ __forceinline__ float bf2f(ushort u) {
    return __uint_as_float((unsigned)u << 16);
}

// ---------------- Kernel 1: xw (blocks < 8192) + weight-cvt (blocks >= 8192) -
__global__ __launch_bounds__(256) void k_xw_wcvt(const float* __restrict__ x,
                                                 const float* __restrict__ W_ih,
                                                 const float* __restrict__ b_ih,
                                                 const float* __restrict__ b_hh,
                                                 float* __restrict__ xw,
                                                 const float* __restrict__ Wp,
                                                 const float* __restrict__ Wqkv,
                                                 const float* __restrict__ Wo,
                                                 const float* __restrict__ W1,
                                                 const float* __restrict__ W2,
                                                 ushort* __restrict__ wout) {
    if (blockIdx.x >= 8192) {
        int i = (blockIdx.x - 8192) * 256 + threadIdx.x;   // 139264 total
        float v;
        if (i < 8192) v = Wp[i];
        else if (i < 57344) {
            int e = i - 8192;
            v = Wqkv[e];
            int row = e >> 7;
            if (row >= 128 && row < 256) v *= 0.36067376f;  // 0.25 * log2(e)
        }
        else if (i < 73728) v = Wo[i - 57344];
        else if (i < 106496) v = W1[i - 73728];
        else v = W2[i - 106496];
        wout[i] = (ushort)f2bf(v);
        return;
    }
    int idx = blockIdx.x * 256 + threadIdx.x;  // over S*B*H = 2M
    int j  = idx & (HH - 1);
    int sb = idx >> 6;          // s*B + b
    int s  = sb >> 6;           // / B
    int b  = sb & (BB - 1);
    const float* xr = x + (b * SS + s) * II;
    const float* wr = W_ih + j * II;
    float acc = b_ih[j] + b_hh[j];
    #pragma unroll
    for (int k = 0; k < II; k += 4) {
        float4 xv = *(const float4*)(xr + k);
        float4 wv = *(const float4*)(wr + k);
        acc += xv.x * wv.x + xv.y * wv.y + xv.z * wv.z + xv.w * wv.w;
    }
    xw[idx] = acc;
}

// ---------------- Kernel 2: RNN recurrence, one block (1 wave) per batch ----
// Inner 64-step loop is the FROZEN R4/R5 body byte-for-byte (134.5us x5).
// New: t-loop tiled 8x64; after each chunk lane 0 release-increments
// prog[chunk] so downstream proj/qkv tiles can start while later chunks
// still run (producer-consumer overlap -- 192 of 256 CUs were idle here).
__global__ __launch_bounds__(64, 1) void k_rnn(const float* __restrict__ xw,
                                               const float* __restrict__ W_hh,
                                               float* __restrict__ hs,
                                               unsigned* __restrict__ prog) {
    int b = blockIdx.x;
    int j = threadIdx.x;
    float w[HH];
    #pragma unroll
    for (int k = 0; k < HH; k++) w[k] = W_hh[j * HH + k];

    float hv = 0.0f;
    float xv0 = xw[(0 * BB + b) * HH + j];
    float xv1 = xw[(1 * BB + b) * HH + j];
    for (int tc = 0; tc < 8; tc++) {
        for (int ti = 0; ti < 64; ti++) {
            int t = tc * 64 + ti;
            int tn = (t < SS - 2) ? t + 2 : t;
            float xnext = xw[(tn * BB + b) * HH + j];  // prefetch depth 2
            float a0 = xv0, a1 = 0.f, a2 = 0.f, a3 = 0.f;
            #pragma unroll
            for (int k = 0; k < HH; k += 4) {
                a0 = fmaf(w[k + 0], bcast(hv, k + 0), a0);
                a1 = fmaf(w[k + 1], bcast(hv, k + 1), a1);
                a2 = fmaf(w[k + 2], bcast(hv, k + 2), a2);
                a3 = fmaf(w[k + 3], bcast(hv, k + 3), a3);
            }
            hv = fast_tanh((a0 + a1) + (a2 + a3));
            hs[(t * BB + b) * HH + j] = hv;   // fire-and-forget
            xv0 = xv1;
            xv1 = xnext;
        }
        if (j == 0)
            __hip_atomic_fetch_add(&prog[tc], 1u, __ATOMIC_RELEASE,
                                   __HIP_MEMORY_SCOPE_AGENT);
    }
}

// ------ Kernel 3a: proj GEMM, fp32 A converted in staging, bf16 W -----------
// Tile x == timestep x. Spins until rnn chunk x>>6 is complete (all 64
// batches), then publishes flag[x] for qkv after its stores are fenced.
template<int K, bool RELU>
__global__ __launch_bounds__(256) void k_gemm_m64fa(const float* __restrict__ A,
                                                    const ushort* __restrict__ W,
                                                    const float* __restrict__ bias,
                                                    ushort* __restrict__ C, int N,
                                                    const unsigned* __restrict__ prog,
                                                    unsigned* __restrict__ flags) {
    if (threadIdx.x == 0) {
        while (__hip_atomic_load(&prog[blockIdx.x >> 6], __ATOMIC_ACQUIRE,
                                 __HIP_MEMORY_SCOPE_AGENT) < 64u)
            __builtin_amdgcn_s_sleep(4);
    }
    __syncthreads();

    __shared__ short As[64 * 40];
    __shared__ short Ws[128 * 40];
    int tid = threadIdx.x;
    int wid = tid >> 6, lane = tid & 63;
    int col = lane & 15, quad = lane >> 4;
    int rowBase = blockIdx.x * 64, colBase = blockIdx.y * 128;

    f32x4 acc[8];
    #pragma unroll
    for (int nt = 0; nt < 8; nt++) {
        float bv = bias[colBase + nt * 16 + col];
        acc[nt][0] = bv; acc[nt][1] = bv; acc[nt][2] = bv; acc[nt][3] = bv;
    }

    int arow = tid >> 2, akc = (tid & 3) * 8;
    int wrow = tid >> 1, wkc = (tid & 1) * 16;

    for (int kb = 0; kb < K; kb += 32) {
        {
            const float4* ap = (const float4*)(A + (size_t)(rowBase + arow) * K + kb + akc);
            float4 v0 = ap[0], v1 = ap[1];
            short t0[8];
            t0[0]=f2bf(v0.x); t0[1]=f2bf(v0.y); t0[2]=f2bf(v0.z); t0[3]=f2bf(v0.w);
            t0[4]=f2bf(v1.x); t0[5]=f2bf(v1.y); t0[6]=f2bf(v1.z); t0[7]=f2bf(v1.w);
            *(int4*)&As[arow * 40 + akc] = *(int4*)t0;
        }
        {
            const int4* wp = (const int4*)(W + (size_t)(colBase + wrow) * K + kb + wkc);
            *(int4*)&Ws[wrow * 40 + wkc]     = wp[0];
            *(int4*)&Ws[wrow * 40 + wkc + 8] = wp[1];
        }
        __syncthreads();

        bf16x8 af = *(const bf16x8*)&As[(wid * 16 + col) * 40 + quad * 8];
        bf16x8 wf[8];
        #pragma unroll
        for (int nt = 0; nt < 8; nt++)
            wf[nt] = *(const bf16x8*)&Ws[(nt * 16 + col) * 40 + quad * 8];
        #pragma unroll
        for (int nt = 0; nt < 8; nt++)
            acc[nt] = __builtin_amdgcn_mfma_f32_16x16x32_bf16(af, wf[nt], acc[nt], 0, 0, 0);
        __syncthreads();
    }

    #pragma unroll
    for (int r = 0; r < 4; r++) {
        int m = rowBase + wid * 16 + quad * 4 + r;
        #pragma unroll
        for (int nt = 0; nt < 8; nt++) {
            float v = acc[nt][r];
            if (RELU) v = fmaxf(v, 0.f);
            C[(size_t)m * N + colBase + nt * 16 + col] = (ushort)f2bf(v);
        }
    }

    __threadfence();
    __syncthreads();
    if (threadIdx.x == 0)
        __hip_atomic_store(&flags[blockIdx.x], 1u, __ATOMIC_RELEASE,
                           __HIP_MEMORY_SCOPE_AGENT);
}

// ------ Kernel 3b: bf16-in GEMM, M=64 x N=128 tile; optional tile spin ------
template<int K, bool RELU, bool OUTBF>
__global__ __launch_bounds__(256) void k_gemm_m64b(const ushort* __restrict__ A,
                                                   const ushort* __restrict__ W,
                                                   const float* __restrict__ bias,
                                                   void* __restrict__ Cv, int N,
                                                   const unsigned* __restrict__ waitflag) {
    if (waitflag) {
        if (threadIdx.x == 0) {
            while (__hip_atomic_load(&waitflag[blockIdx.x], __ATOMIC_ACQUIRE,
                                     __HIP_MEMORY_SCOPE_AGENT) == 0u)
                __builtin_amdgcn_s_sleep(4);
        }
        __syncthreads();
    }

    __shared__ short As[64 * 40];
    __shared__ short Ws[128 * 40];
    int tid = threadIdx.x;
    int wid = tid >> 6, lane = tid & 63;
    int col = lane & 15, quad = lane >> 4;
    int rowBase = blockIdx.x * 64, colBase = blockIdx.y * 128;

    f32x4 acc[8];
    #pragma unroll
    for (int nt = 0; nt < 8; nt++) {
        float bv = bias[colBase + nt * 16 + col];
        acc[nt][0] = bv; acc[nt][1] = bv; acc[nt][2] = bv; acc[nt][3] = bv;
    }

    int arow = tid >> 2, akc = (tid & 3) * 8;    // A: 8 bf16 (16B) each
    int wrow = tid >> 1, wkc = (tid & 1) * 16;   // W: 16 bf16 (32B) each

    for (int kb = 0; kb < K; kb += 32) {
        *(int4*)&As[arow * 40 + akc] =
            *(const int4*)(A + (size_t)(rowBase + arow) * K + kb + akc);
        {
            const int4* wp = (const int4*)(W + (size_t)(colBase + wrow) * K + kb + wkc);
            *(int4*)&Ws[wrow * 40 + wkc]     = wp[0];
            *(int4*)&Ws[wrow * 40 + wkc + 8] = wp[1];
        }
        __syncthreads();

        bf16x8 af = *(const bf16x8*)&As[(wid * 16 + col) * 40 + quad * 8];
        bf16x8 wf[8];
        #pragma unroll
        for (int nt = 0; nt < 8; nt++)
            wf[nt] = *(const bf16x8*)&Ws[(nt * 16 + col) * 40 + quad * 8];
        #pragma unroll
        for (int nt = 0; nt < 8; nt++)
            acc[nt] = __builtin_amdgcn_mfma_f32_16x16x32_bf16(af, wf[nt], acc[nt], 0, 0, 0);
        __syncthreads();
    }

    #pragma unroll
    for (int r = 0; r < 4; r++) {
        int m = rowBase + wid * 16 + quad * 4 + r;
        #pragma unroll
        for (int nt = 0; nt < 8; nt++) {
            float v = acc[nt][r];
            if (RELU) v = fmaxf(v, 0.f);
            if (OUTBF)
                ((ushort*)Cv)[(size_t)m * N + colBase + nt * 16 + col] = (ushort)f2bf(v);
            else
                ((float*)Cv)[(size_t)m * N + colBase + nt * 16 + col] = v;
        }
    }
}

// ------- GEMM (M=64 tile, N=DD) with fused LayerNorm(s), bf16 in ------------
template<int K, int NLN, bool OUTBF>
__global__ __launch_bounds__(256) void k_gemm_ln_m64b(const ushort* __restrict__ A,
                                                      const ushort* __restrict__ W,
                                                      const float* __restrict__ bias,
                                                      const ushort* __restrict__ res1,
                                                      const float* __restrict__ g1v,
                                                      const float* __restrict__ be1v,
                                                      const ushort* __restrict__ res2,
                                                      const float* __restrict__ g2v,
                                                      const float* __restrict__ be2v,
                                                      void* __restrict__ outv) {
    __shared__ short As[64 * 40];
    __shared__ short Ws[128 * 40];
    int tid = threadIdx.x;
    int wid = tid >> 6, lane = tid & 63;
    int col = lane & 15, quad = lane >> 4;
    int rowBase = blockIdx.x * 64;

    f32x4 acc[8];
    #pragma unroll
    for (int nt = 0; nt < 8; nt++) {
        float bv = bias[nt * 16 + col];
        acc[nt][0] = bv; acc[nt][1] = bv; acc[nt][2] = bv; acc[nt][3] = bv;
    }

    int arow = tid >> 2, akc = (tid & 3) * 8;
    int wrow = tid >> 1, wkc = (tid & 1) * 16;

    for (int kb = 0; kb < K; kb += 32) {
        *(int4*)&As[arow * 40 + akc] =
            *(const int4*)(A + (size_t)(rowBase + arow) * K + kb + akc);
        {
            const int4* wp = (const int4*)(W + (size_t)wrow * K + kb + wkc);
            *(int4*)&Ws[wrow * 40 + wkc]     = wp[0];
            *(int4*)&Ws[wrow * 40 + wkc + 8] = wp[1];
        }
        __syncthreads();

        bf16x8 af = *(const bf16x8*)&As[(wid * 16 + col) * 40 + quad * 8];
        bf16x8 wf[8];
        #pragma unroll
        for (int nt = 0; nt < 8; nt++)
            wf[nt] = *(const bf16x8*)&Ws[(nt * 16 + col) * 40 + quad * 8];
        #pragma unroll
        for (int nt = 0; nt < 8; nt++)
            acc[nt] = __builtin_amdgcn_mfma_f32_16x16x32_bf16(af, wf[nt], acc[nt], 0, 0, 0);
        __syncthreads();
    }

    float ga[8], ba[8], gb[8], bb[8];
    #pragma unroll
    for (int nt = 0; nt < 8; nt++) {
        ga[nt] = g1v[nt * 16 + col]; ba[nt] = be1v[nt * 16 + col];
        if (NLN == 2) { gb[nt] = g2v[nt * 16 + col]; bb[nt] = be2v[nt * 16 + col]; }
    }

    #pragma unroll
    for (int r = 0; r < 4; r++) {
        int m = rowBase + wid * 16 + quad * 4 + r;
        const ushort* rr1 = res1 + (size_t)m * DD;
        float v[8];
        float s = 0.f;
        #pragma unroll
        for (int nt = 0; nt < 8; nt++) {
            v[nt] = acc[nt][r] + bf2f(rr1[nt * 16 + col]);
            s += v[nt];
        }
        #pragma unroll
        for (int off = 1; off < 16; off <<= 1) s += __shfl_xor(s, off, 64);
        float mu = s * (1.0f / 128.0f);
        float vs = 0.f;
        #pragma unroll
        for (int nt = 0; nt < 8; nt++) { v[nt] -= mu; vs += v[nt] * v[nt]; }
        #pragma unroll
        for (int off = 1; off < 16; off <<= 1) vs += __shfl_xor(vs, off, 64);
        float rstd = rsqrtf(vs * (1.0f / 128.0f) + 1e-5f);
        #pragma unroll
        for (int nt = 0; nt < 8; nt++) v[nt] = v[nt] * rstd * ga[nt] + ba[nt];

        if (NLN == 2) {
            const ushort* rr2 = res2 + (size_t)m * DD;
            float s2 = 0.f;
            #pragma unroll
            for (int nt = 0; nt < 8; nt++) {
                v[nt] += bf2f(rr2[nt * 16 + col]);
                s2 += v[nt];
            }
            #pragma unroll
            for (int off = 1; off < 16; off <<= 1) s2 += __shfl_xor(s2, off, 64);
            float mu2 = s2 * (1.0f / 128.0f);
            float vs2 = 0.f;
            #pragma unroll
            for (int nt = 0; nt < 8; nt++) { v[nt] -= mu2; vs2 += v[nt] * v[nt]; }
            #pragma unroll
            for (int off = 1; off < 16; off <<= 1) vs2 += __shfl_xor(vs2, off, 64);
            float rstd2 = rsqrtf(vs2 * (1.0f / 128.0f) + 1e-5f);
            #pragma unroll
            for (int nt = 0; nt < 8; nt++) v[nt] = v[nt] * rstd2 * gb[nt] + bb[nt];
        }

        #pragma unroll
        for (int nt = 0; nt < 8; nt++) {
            if (OUTBF)
                ((ushort*)outv)[(size_t)m * DD + nt * 16 + col] = (ushort)f2bf(v[nt]);
            else
                ((float*)outv)[(size_t)m * DD + nt * 16 + col] = v[nt];
        }
    }
}

// ---------------- Kernel 4: MFMA flash attention, bf16 qkv (R15 form) -------
__global__ __launch_bounds__(256, 2) void k_attn(const ushort* __restrict__ qkv,
                                                 ushort* __restrict__ ctx) {
    int bh = blockIdx.x;
    int b = bh >> 3, h = bh & 7;
    __shared__ short Vt[HDIM][SS];         // [d][k'] permuted within 64-chunks
    __shared__ short Pb[4][2][16 * 64];    // [wave][dbuf][qrow][64 k']
    int tid = threadIdx.x;

    for (int t = tid; t < SS; t += 256) {
        const ushort* base = qkv + (size_t)(t * BB + b) * 384 + 256 + h * 16;
        int4 va = *(const int4*)base;
        int4 vb = *(const int4*)(base + 8);
        const ushort* pa = (const ushort*)&va;
        const ushort* pb = (const ushort*)&vb;
        int u = t & 63;
        int pos = (t & ~63) | (((u & 15) << 2) | (u >> 4));
        #pragma unroll
        for (int d = 0; d < 8; d++) {
            Vt[d][pos]     = pa[d];
            Vt[d + 8][pos] = pb[d];
        }
    }
    __syncthreads();

    int wid = tid >> 6, lane = tid & 63;
    int col = lane & 15, quad = lane >> 4;

    bf16x8 kf[32];
    #pragma unroll
    for (int kt = 0; kt < 32; kt++) {
        bf16x8 f = (bf16x8)(short)0;
        if (quad < 2)
            f = *(const bf16x8*)(qkv + (size_t)((kt * 16 + col) * BB + b) * 384
                                 + 128 + h * 16 + quad * 8);
        kf[kt] = f;
    }

    for (int sub = 0; sub < 8; sub++) {
        int q0 = wid * 128 + sub * 16;

        bf16x8 qf = (bf16x8)(short)0;
        if (quad < 2)
            qf = *(const bf16x8*)(qkv + (size_t)((q0 + col) * BB + b) * 384
                                  + h * 16 + quad * 8);

        float l0 = 0.f, l1 = 0.f, l2 = 0.f, l3 = 0.f;
        f32x4 O = {0.f, 0.f, 0.f, 0.f};
        #pragma unroll
        for (int c = 0; c < 8; c++) {
            short* pbuf = &Pb[wid][c & 1][0];
            float p[4][4];
            #pragma unroll
            for (int kk = 0; kk < 4; kk++) {
                f32x4 z = {0.f, 0.f, 0.f, 0.f};
                f32x4 S = __builtin_amdgcn_mfma_f32_16x16x32_bf16(qf, kf[c * 4 + kk], z, 0, 0, 0);
                p[kk][0] = exp2f(S[0]); p[kk][1] = exp2f(S[1]);
                p[kk][2] = exp2f(S[2]); p[kk][3] = exp2f(S[3]);
                l0 += p[kk][0]; l1 += p[kk][1]; l2 += p[kk][2]; l3 += p[kk][3];
            }
            #pragma unroll
            for (int r = 0; r < 4; r++) {
                unsigned w0 = (unsigned)(unsigned short)f2bf(p[0][r])
                            | ((unsigned)(unsigned short)f2bf(p[1][r]) << 16);
                unsigned w1 = (unsigned)(unsigned short)f2bf(p[2][r])
                            | ((unsigned)(unsigned short)f2bf(p[3][r]) << 16);
                *(uint2*)&pbuf[(4 * quad + r) * 64 + col * 4] = make_uint2(w0, w1);
            }
            #pragma unroll
            for (int half = 0; half < 2; half++) {
                int tb = c * 64 + half * 32;
                bf16x8 pf = *(const bf16x8*)&pbuf[col * 64 + half * 32 + quad * 8];
                bf16x8 vf = *(const bf16x8*)&Vt[col][tb + quad * 8];
                O = __builtin_amdgcn_mfma_f32_16x16x32_bf16(pf, vf, O, 0, 0, 0);
            }
        }

        float l[4] = {l0, l1, l2, l3};
        #pragma unroll
        for (int r = 0; r < 4; r++) {
            #pragma unroll
            for (int off = 1; off < 16; off <<= 1) l[r] += __shfl_xor(l[r], off, 64);
            float inv = __builtin_amdgcn_rcpf(l[r]);
            int q = q0 + 4 * quad + r;
            ctx[(size_t)(q * BB + b) * DD + h * 16 + col] = (ushort)f2bf(O[r] * inv);
        }
    }
}

// ---------------- Kernel 5: fused mean-pool + head (outln fp32) -------------
__global__ __launch_bounds__(256) void k_poolfinal(const float* __restrict__ outln,
                                                   const float* __restrict__ Wf,
                                                   const float* __restrict__ bfv,
                                                   float* __restrict__ out) {
    int b = blockIdx.x;
    int tid = threadIdx.x;
    __shared__ float part[256];
    __shared__ float pooled[128];
    int d = tid & 127, half = tid >> 7;
    float s = 0.f;
    int s0 = half * 256;
    #pragma unroll 8
    for (int si = s0; si < s0 + 256; si++)
        s += outln[(size_t)(si * BB + b) * DD + d];
    part[tid] = s;
    __syncthreads();
    if (tid < 128) pooled[tid] = (part[tid] + part[tid + 128]) * (1.0f / SS);
    __syncthreads();
    if (tid < 32) {
        const float* wr = Wf + tid * DD;
        float acc = bfv[tid];
        #pragma unroll
        for (int k = 0; k < DD; k += 4) {
            float4 wv = *(const float4*)(wr + k);
            acc += pooled[k] * wv.x + pooled[k + 1] * wv.y
                 + pooled[k + 2] * wv.z + pooled[k + 3] * wv.w;
        }
        out[b * 32 + tid] = fast_tanh(acc);
    }
}

extern "C" void kernel_launch(void* const* d_in, const int* in_sizes, int n_in,
                              void* d_out, int out_size, void* d_ws, size_t ws_size,
                              hipStream_t stream) {
    const float* x    = (const float*)d_in[0];
    const float* W_ih = (const float*)d_in[1];
    const float* b_ih = (const float*)d_in[2];
    const float* W_hh = (const float*)d_in[3];
    const float* b_hh = (const float*)d_in[4];
    const float* Wp   = (const float*)d_in[5];
    const float* bp   = (const float*)d_in[6];
    const float* Wqkv = (const float*)d_in[7];
    const float* bqkv = (const float*)d_in[8];
    const float* Wo   = (const float*)d_in[9];
    const float* bo   = (const float*)d_in[10];
    const float* g1   = (const float*)d_in[11];
    const float* be1  = (const float*)d_in[12];
    const float* W1   = (const float*)d_in[13];
    const float* b1   = (const float*)d_in[14];
    const float* W2   = (const float*)d_in[15];
    const float* b2   = (const float*)d_in[16];
    const float* g2   = (const float*)d_in[17];
    const float* be2  = (const float*)d_in[18];
    const float* gn   = (const float*)d_in[19];
    const float* bn   = (const float*)d_in[20];
    const float* Wf   = (const float*)d_in[21];
    const float* bf   = (const float*)d_in[22];
    float* out = (float*)d_out;
    char* wsb = (char*)d_ws;

    // workspace layout (bytes); bf16 intermediates. ~96.3 MB + sync.
    float*  xw    = (float*)(wsb);                      // 8MB   [xw .. rnn]
    float*  hsf   = (float*)(wsb + (8u << 20));         // 8MB   [rnn .. proj]
    ushort* projb = (ushort*)(wsb + (16u << 20));       // 8MB   [proj .. end]
    ushort* qkvb  = (ushort*)(wsb + (24u << 20));       // 24MB  [qkv .. attn]
    ushort* ctxb  = (ushort*)(wsb + (48u << 20));       // 8MB   [attn .. Wo]
    ushort* x1b   = (ushort*)(wsb + (56u << 20));       // 8MB   [Wo .. ff2]
    ushort* ff1b  = (ushort*)(wsb + (64u << 20));       // 16MB  [ff1 .. ff2]
    float*  outln = (float*)(wsb + (80u << 20));        // 16MB  [ff2 .. pool]
    ushort* wbf   = (ushort*)(wsb + (96u << 20));       // 0.28MB weights
    ushort* Wp_bf   = wbf;
    ushort* Wqkv_bf = wbf + 8192;
    ushort* Wo_bf   = wbf + 57344;
    ushort* W1_bf   = wbf + 73728;
    ushort* W2_bf   = wbf + 106496;
    unsigned* sync  = (unsigned*)(wsb + (97u << 20));   // prog[8] + flags[512]
    unsigned* prog  = sync;
    unsigned* flags = sync + 8;

    hipMemsetAsync(sync, 0, (8 + 512) * sizeof(unsigned), stream);
    k_xw_wcvt<<<8736, 256, 0, stream>>>(x, W_ih, b_ih, b_hh, xw,
                                        Wp, Wqkv, Wo, W1, W2, wbf);
    k_rnn<<<64, 64, 0, stream>>>(xw, W_hh, hsf, prog);
    // proj tiles spin on rnn chunk progress; qkv tiles spin on proj flags.
    // Both overlap with the rnn's 134us (192 idle CUs).
    k_gemm_m64fa<64, false><<<dim3(512, 1), 256, 0, stream>>>(hsf, Wp_bf, bp, projb, 128,
                                                              prog, flags);
    k_gemm_m64b<128, false, true><<<dim3(512, 3), 256, 0, stream>>>(projb, Wqkv_bf, bqkv,
                                                                    qkvb, 384, flags);
    k_attn<<<512, 256, 0, stream>>>(qkvb, ctxb);
    // x1 = LN1(proj + ctx@Wo^T + bo)
    k_gemm_ln_m64b<128, 1, true><<<512, 256, 0, stream>>>(ctxb, Wo_bf, bo, projb, g1, be1,
                                                          nullptr, nullptr, nullptr, x1b);
    k_gemm_m64b<128, true, true><<<dim3(512, 2), 256, 0, stream>>>(x1b, W1_bf, b1, ff1b,
                                                                   256, nullptr);
    // outln = LN3( LN2(x1 + ff1@W2^T + b2) + proj )   (fp32 out for pool)
    k_gemm_ln_m64b<256, 2, false><<<512, 256, 0, stream>>>(ff1b, W2_bf, b2, x1b, g2, be2,
                                                           projb, gn, bn, outln);
    k_poolfinal<<<64, 256, 0, stream>>>(outln, Wf, bf, out);
}

// Round 18
// 396.690 us; speedup vs baseline: 1.2428x; 1.2428x over previous
//
#include <hip/hip_runtime.h>
#include <hip/hip_bf16.h>

#define BB 64
#define SS 512
#define II 32
#define HH 64
#define DD 128
#define FF 256
#define NHEAD 8
#define HDIM 16
#define NTOK (SS*BB)   // 32768

typedef short bf16x8 __attribute__((ext_vector_type(8)));
typedef float f32x4  __attribute__((ext_vector_type(4)));

__device__ __forceinline__ float fast_tanh(float x) {
    float ax = fabsf(x);
    float e = __expf(-2.0f * ax);
    float r = (1.0f - e) * __builtin_amdgcn_rcpf(1.0f + e);
    return copysignf(r, x);
}

__device__ __forceinline__ float bcast(float v, int lane) {
    return __int_as_float(__builtin_amdgcn_readlane(__float_as_int(v), lane));
}

// fp32 -> bf16 bits, round-to-nearest-even
__device__ __forceinline__ short f2bf(float x) {
    unsigned u = __float_as_uint(x);
    return (short)((u + 0x7FFFu + ((u >> 16) & 1u)) >> 16);
}
__device__ __forceinline__ float bf2f(ushort u) {
    return __uint_as_float((unsigned)u << 16);
}

// ---- Kernel 1: xw (bid<8192) | weight-cvt (<8736) | Wqkv@Wp fold (<8832) ----
// Fold: qkv = hs @ (Wqkv.Wp)^T + (Wqkv.bp + bqkv) -- exact linear algebra,
// computed in fp32, rounded ONCE to bf16. Attention q/k scale (0.25*log2e)
// folded into rows 128..255 of W' and b'. This makes qkv depend only on hs
// (mergeable with proj) and halves its K (128 -> 64).
__global__ __launch_bounds__(256) void k_xw_wcvt(const float* __restrict__ x,
                                                 const float* __restrict__ W_ih,
                                                 const float* __restrict__ b_ih,
                                                 const float* __restrict__ b_hh,
                                                 float* __restrict__ xw,
                                                 const float* __restrict__ Wp,
                                                 const float* __restrict__ Wqkv,
                                                 const float* __restrict__ Wo,
                                                 const float* __restrict__ W1,
                                                 const float* __restrict__ W2,
                                                 const float* __restrict__ bp,
                                                 const float* __restrict__ bqkv,
                                                 ushort* __restrict__ wout,
                                                 ushort* __restrict__ Wq2,
                                                 float* __restrict__ bq2) {
    if (blockIdx.x >= 8736) {   // fold blocks
        int i = (blockIdx.x - 8736) * 256 + threadIdx.x;   // 24576 total
        int n = i >> 6, k = i & 63;
        const float* wr = Wqkv + n * DD;
        float acc = 0.f;
        #pragma unroll 4
        for (int d = 0; d < DD; d++) acc += wr[d] * Wp[d * HH + k];
        float scale = (n >= 128 && n < 256) ? 0.36067376f : 1.0f;
        Wq2[n * HH + k] = (ushort)f2bf(acc * scale);
        if (k == 0) {
            float bacc = bqkv[n];
            for (int d = 0; d < DD; d++) bacc += wr[d] * bp[d];
            bq2[n] = bacc * scale;
        }
        return;
    }
    if (blockIdx.x >= 8192) {   // weight conversion blocks
        int i = (blockIdx.x - 8192) * 256 + threadIdx.x;   // 139264 total
        float v;
        if (i < 8192) v = Wp[i];
        else if (i < 57344) v = Wqkv[i - 8192];   // kept for layout stability
        else if (i < 73728) v = Wo[i - 57344];
        else if (i < 106496) v = W1[i - 73728];
        else v = W2[i - 106496];
        wout[i] = (ushort)f2bf(v);
        return;
    }
    int idx = blockIdx.x * 256 + threadIdx.x;  // over S*B*H = 2M
    int j  = idx & (HH - 1);
    int sb = idx >> 6;          // s*B + b
    int s  = sb >> 6;           // / B
    int b  = sb & (BB - 1);
    const float* xr = x + (b * SS + s) * II;
    const float* wr = W_ih + j * II;
    float acc = b_ih[j] + b_hh[j];
    #pragma unroll
    for (int k = 0; k < II; k += 4) {
        float4 xv = *(const float4*)(xr + k);
        float4 wv = *(const float4*)(wr + k);
        acc += xv.x * wv.x + xv.y * wv.y + xv.z * wv.z + xv.w * wv.w;
    }
    xw[idx] = acc;
}

// ---------------- Kernel 2: RNN recurrence, one block (1 wave) per batch ----
// FROZEN: byte-for-byte the R4/R5 body -- 134.5us x5. Eight variants lost
// (incl. R17's chunk+atomic: 150us + consumer-spin interference).
// DO NOT TOUCH.
__global__ __launch_bounds__(64, 1) void k_rnn(const float* __restrict__ xw,
                                               const float* __restrict__ W_hh,
                                               float* __restrict__ hs) {
    int b = blockIdx.x;
    int j = threadIdx.x;
    float w[HH];
    #pragma unroll
    for (int k = 0; k < HH; k++) w[k] = W_hh[j * HH + k];

    float hv = 0.0f;
    float xv0 = xw[(0 * BB + b) * HH + j];
    float xv1 = xw[(1 * BB + b) * HH + j];
    for (int t = 0; t < SS; t++) {
        int tn = (t < SS - 2) ? t + 2 : t;
        float xnext = xw[(tn * BB + b) * HH + j];  // prefetch depth 2
        float a0 = xv0, a1 = 0.f, a2 = 0.f, a3 = 0.f;
        #pragma unroll
        for (int k = 0; k < HH; k += 4) {
            a0 = fmaf(w[k + 0], bcast(hv, k + 0), a0);
            a1 = fmaf(w[k + 1], bcast(hv, k + 1), a1);
            a2 = fmaf(w[k + 2], bcast(hv, k + 2), a2);
            a3 = fmaf(w[k + 3], bcast(hv, k + 3), a3);
        }
        hv = fast_tanh((a0 + a1) + (a2 + a3));
        hs[(t * BB + b) * HH + j] = hv;   // fire-and-forget
        xv0 = xv1;
        xv1 = xnext;
    }
}

// ------ Kernel 3: merged proj+qkv, both K=64 from fp32 hs -------------------
// bid < 512: proj tile (W=Wp_bf, N=128). bid >= 512: qkv tile from folded
// W' (N=384, 3 col-tiles). One dispatch, one fewer gap; qkv K halved.
__global__ __launch_bounds__(256) void k_projqkv(const float* __restrict__ hsf,
                                                 const ushort* __restrict__ Wp_bf,
                                                 const float* __restrict__ bp,
                                                 ushort* __restrict__ projb,
                                                 const ushort* __restrict__ Wq2,
                                                 const float* __restrict__ bq2,
                                                 ushort* __restrict__ qkvb) {
    const int K = 64;
    int bid = blockIdx.x;
    const ushort* W; const float* bias; ushort* C; int N, rowBase, colBase;
    if (bid < 512) {
        W = Wp_bf; bias = bp; C = projb; N = 128;
        rowBase = bid * 64; colBase = 0;
    } else {
        int e = bid - 512;
        W = Wq2; bias = bq2; C = qkvb; N = 384;
        rowBase = (e & 511) * 64; colBase = (e >> 9) * 128;
    }

    __shared__ short As[64 * 40];
    __shared__ short Ws[128 * 40];
    int tid = threadIdx.x;
    int wid = tid >> 6, lane = tid & 63;
    int col = lane & 15, quad = lane >> 4;

    f32x4 acc[8];
    #pragma unroll
    for (int nt = 0; nt < 8; nt++) {
        float bv = bias[colBase + nt * 16 + col];
        acc[nt][0] = bv; acc[nt][1] = bv; acc[nt][2] = bv; acc[nt][3] = bv;
    }

    int arow = tid >> 2, akc = (tid & 3) * 8;
    int wrow = tid >> 1, wkc = (tid & 1) * 16;

    #pragma unroll
    for (int kb = 0; kb < K; kb += 32) {
        {
            const float4* ap = (const float4*)(hsf + (size_t)(rowBase + arow) * K + kb + akc);
            float4 v0 = ap[0], v1 = ap[1];
            short t0[8];
            t0[0]=f2bf(v0.x); t0[1]=f2bf(v0.y); t0[2]=f2bf(v0.z); t0[3]=f2bf(v0.w);
            t0[4]=f2bf(v1.x); t0[5]=f2bf(v1.y); t0[6]=f2bf(v1.z); t0[7]=f2bf(v1.w);
            *(int4*)&As[arow * 40 + akc] = *(int4*)t0;
        }
        {
            const int4* wp = (const int4*)(W + (size_t)(colBase + wrow) * K + kb + wkc);
            *(int4*)&Ws[wrow * 40 + wkc]     = wp[0];
            *(int4*)&Ws[wrow * 40 + wkc + 8] = wp[1];
        }
        __syncthreads();

        bf16x8 af = *(const bf16x8*)&As[(wid * 16 + col) * 40 + quad * 8];
        bf16x8 wf[8];
        #pragma unroll
        for (int nt = 0; nt < 8; nt++)
            wf[nt] = *(const bf16x8*)&Ws[(nt * 16 + col) * 40 + quad * 8];
        #pragma unroll
        for (int nt = 0; nt < 8; nt++)
            acc[nt] = __builtin_amdgcn_mfma_f32_16x16x32_bf16(af, wf[nt], acc[nt], 0, 0, 0);
        __syncthreads();
    }

    #pragma unroll
    for (int r = 0; r < 4; r++) {
        int m = rowBase + wid * 16 + quad * 4 + r;
        #pragma unroll
        for (int nt = 0; nt < 8; nt++)
            C[(size_t)m * N + colBase + nt * 16 + col] = (ushort)f2bf(acc[nt][r]);
    }
}

// ------ Kernel 3b: bf16-in GEMM, M=64 x N=128 tile (R16 form) ---------------
template<int K, bool RELU, bool OUTBF>
__global__ __launch_bounds__(256) void k_gemm_m64b(const ushort* __restrict__ A,
                                                   const ushort* __restrict__ W,
                                                   const float* __restrict__ bias,
                                                   void* __restrict__ Cv, int N) {
    __shared__ short As[64 * 40];
    __shared__ short Ws[128 * 40];
    int tid = threadIdx.x;
    int wid = tid >> 6, lane = tid & 63;
    int col = lane & 15, quad = lane >> 4;
    int rowBase = blockIdx.x * 64, colBase = blockIdx.y * 128;

    f32x4 acc[8];
    #pragma unroll
    for (int nt = 0; nt < 8; nt++) {
        float bv = bias[colBase + nt * 16 + col];
        acc[nt][0] = bv; acc[nt][1] = bv; acc[nt][2] = bv; acc[nt][3] = bv;
    }

    int arow = tid >> 2, akc = (tid & 3) * 8;    // A: 8 bf16 (16B) each
    int wrow = tid >> 1, wkc = (tid & 1) * 16;   // W: 16 bf16 (32B) each

    for (int kb = 0; kb < K; kb += 32) {
        *(int4*)&As[arow * 40 + akc] =
            *(const int4*)(A + (size_t)(rowBase + arow) * K + kb + akc);
        {
            const int4* wp = (const int4*)(W + (size_t)(colBase + wrow) * K + kb + wkc);
            *(int4*)&Ws[wrow * 40 + wkc]     = wp[0];
            *(int4*)&Ws[wrow * 40 + wkc + 8] = wp[1];
        }
        __syncthreads();

        bf16x8 af = *(const bf16x8*)&As[(wid * 16 + col) * 40 + quad * 8];
        bf16x8 wf[8];
        #pragma unroll
        for (int nt = 0; nt < 8; nt++)
            wf[nt] = *(const bf16x8*)&Ws[(nt * 16 + col) * 40 + quad * 8];
        #pragma unroll
        for (int nt = 0; nt < 8; nt++)
            acc[nt] = __builtin_amdgcn_mfma_f32_16x16x32_bf16(af, wf[nt], acc[nt], 0, 0, 0);
        __syncthreads();
    }

    #pragma unroll
    for (int r = 0; r < 4; r++) {
        int m = rowBase + wid * 16 + quad * 4 + r;
        #pragma unroll
        for (int nt = 0; nt < 8; nt++) {
            float v = acc[nt][r];
            if (RELU) v = fmaxf(v, 0.f);
            if (OUTBF)
                ((ushort*)Cv)[(size_t)m * N + colBase + nt * 16 + col] = (ushort)f2bf(v);
            else
                ((float*)Cv)[(size_t)m * N + colBase + nt * 16 + col] = v;
        }
    }
}

// ------- GEMM (M=64 tile, N=DD) with fused LayerNorm(s), bf16 in ------------
template<int K, int NLN, bool OUTBF>
__global__ __launch_bounds__(256) void k_gemm_ln_m64b(const ushort* __restrict__ A,
                                                      const ushort* __restrict__ W,
                                                      const float* __restrict__ bias,
                                                      const ushort* __restrict__ res1,
                                                      const float* __restrict__ g1v,
                                                      const float* __restrict__ be1v,
                                                      const ushort* __restrict__ res2,
                                                      const float* __restrict__ g2v,
                                                      const float* __restrict__ be2v,
                                                      void* __restrict__ outv) {
    __shared__ short As[64 * 40];
    __shared__ short Ws[128 * 40];
    int tid = threadIdx.x;
    int wid = tid >> 6, lane = tid & 63;
    int col = lane & 15, quad = lane >> 4;
    int rowBase = blockIdx.x * 64;

    f32x4 acc[8];
    #pragma unroll
    for (int nt = 0; nt < 8; nt++) {
        float bv = bias[nt * 16 + col];
        acc[nt][0] = bv; acc[nt][1] = bv; acc[nt][2] = bv; acc[nt][3] = bv;
    }

    int arow = tid >> 2, akc = (tid & 3) * 8;
    int wrow = tid >> 1, wkc = (tid & 1) * 16;

    for (int kb = 0; kb < K; kb += 32) {
        *(int4*)&As[arow * 40 + akc] =
            *(const int4*)(A + (size_t)(rowBase + arow) * K + kb + akc);
        {
            const int4* wp = (const int4*)(W + (size_t)wrow * K + kb + wkc);
            *(int4*)&Ws[wrow * 40 + wkc]     = wp[0];
            *(int4*)&Ws[wrow * 40 + wkc + 8] = wp[1];
        }
        __syncthreads();

        bf16x8 af = *(const bf16x8*)&As[(wid * 16 + col) * 40 + quad * 8];
        bf16x8 wf[8];
        #pragma unroll
        for (int nt = 0; nt < 8; nt++)
            wf[nt] = *(const bf16x8*)&Ws[(nt * 16 + col) * 40 + quad * 8];
        #pragma unroll
        for (int nt = 0; nt < 8; nt++)
            acc[nt] = __builtin_amdgcn_mfma_f32_16x16x32_bf16(af, wf[nt], acc[nt], 0, 0, 0);
        __syncthreads();
    }

    float ga[8], ba[8], gb[8], bb[8];
    #pragma unroll
    for (int nt = 0; nt < 8; nt++) {
        ga[nt] = g1v[nt * 16 + col]; ba[nt] = be1v[nt * 16 + col];
        if (NLN == 2) { gb[nt] = g2v[nt * 16 + col]; bb[nt] = be2v[nt * 16 + col]; }
    }

    #pragma unroll
    for (int r = 0; r < 4; r++) {
        int m = rowBase + wid * 16 + quad * 4 + r;
        const ushort* rr1 = res1 + (size_t)m * DD;
        float v[8];
        float s = 0.f;
        #pragma unroll
        for (int nt = 0; nt < 8; nt++) {
            v[nt] = acc[nt][r] + bf2f(rr1[nt * 16 + col]);
            s += v[nt];
        }
        #pragma unroll
        for (int off = 1; off < 16; off <<= 1) s += __shfl_xor(s, off, 64);
        float mu = s * (1.0f / 128.0f);
        float vs = 0.f;
        #pragma unroll
        for (int nt = 0; nt < 8; nt++) { v[nt] -= mu; vs += v[nt] * v[nt]; }
        #pragma unroll
        for (int off = 1; off < 16; off <<= 1) vs += __shfl_xor(vs, off, 64);
        float rstd = rsqrtf(vs * (1.0f / 128.0f) + 1e-5f);
        #pragma unroll
        for (int nt = 0; nt < 8; nt++) v[nt] = v[nt] * rstd * ga[nt] + ba[nt];

        if (NLN == 2) {
            const ushort* rr2 = res2 + (size_t)m * DD;
            float s2 = 0.f;
            #pragma unroll
            for (int nt = 0; nt < 8; nt++) {
                v[nt] += bf2f(rr2[nt * 16 + col]);
                s2 += v[nt];
            }
            #pragma unroll
            for (int off = 1; off < 16; off <<= 1) s2 += __shfl_xor(s2, off, 64);
            float mu2 = s2 * (1.0f / 128.0f);
            float vs2 = 0.f;
            #pragma unroll
            for (int nt = 0; nt < 8; nt++) { v[nt] -= mu2; vs2 += v[nt] * v[nt]; }
            #pragma unroll
            for (int off = 1; off < 16; off <<= 1) vs2 += __shfl_xor(vs2, off, 64);
            float rstd2 = rsqrtf(vs2 * (1.0f / 128.0f) + 1e-5f);
            #pragma unroll
            for (int nt = 0; nt < 8; nt++) v[nt] = v[nt] * rstd2 * gb[nt] + bb[nt];
        }

        #pragma unroll
        for (int nt = 0; nt < 8; nt++) {
            if (OUTBF)
                ((ushort*)outv)[(size_t)m * DD + nt * 16 + col] = (ushort)f2bf(v[nt]);
            else
                ((float*)outv)[(size_t)m * DD + nt * 16 + col] = v[nt];
        }
    }
}

// ---------------- Kernel 4: MFMA flash attention, bf16 qkv (R15 form) -------
__global__ __launch_bounds__(256, 2) void k_attn(const ushort* __restrict__ qkv,
                                                 ushort* __restrict__ ctx) {
    int bh = blockIdx.x;
    int b = bh >> 3, h = bh & 7;
    __shared__ short Vt[HDIM][SS];         // [d][k'] permuted within 64-chunks
    __shared__ short Pb[4][2][16 * 64];    // [wave][dbuf][qrow][64 k']
    int tid = threadIdx.x;

    for (int t = tid; t < SS; t += 256) {
        const ushort* base = qkv + (size_t)(t * BB + b) * 384 + 256 + h * 16;
        int4 va = *(const int4*)base;
        int4 vb = *(const int4*)(base + 8);
        const ushort* pa = (const ushort*)&va;
        const ushort* pb = (const ushort*)&vb;
        int u = t & 63;
        int pos = (t & ~63) | (((u & 15) << 2) | (u >> 4));
        #pragma unroll
        for (int d = 0; d < 8; d++) {
            Vt[d][pos]     = pa[d];
            Vt[d + 8][pos] = pb[d];
        }
    }
    __syncthreads();

    int wid = tid >> 6, lane = tid & 63;
    int col = lane & 15, quad = lane >> 4;

    bf16x8 kf[32];
    #pragma unroll
    for (int kt = 0; kt < 32; kt++) {
        bf16x8 f = (bf16x8)(short)0;
        if (quad < 2)
            f = *(const bf16x8*)(qkv + (size_t)((kt * 16 + col) * BB + b) * 384
                                 + 128 + h * 16 + quad * 8);
        kf[kt] = f;
    }

    for (int sub = 0; sub < 8; sub++) {
        int q0 = wid * 128 + sub * 16;

        bf16x8 qf = (bf16x8)(short)0;
        if (quad < 2)
            qf = *(const bf16x8*)(qkv + (size_t)((q0 + col) * BB + b) * 384
                                  + h * 16 + quad * 8);

        float l0 = 0.f, l1 = 0.f, l2 = 0.f, l3 = 0.f;
        f32x4 O = {0.f, 0.f, 0.f, 0.f};
        #pragma unroll
        for (int c = 0; c < 8; c++) {
            short* pbuf = &Pb[wid][c & 1][0];
            float p[4][4];
            #pragma unroll
            for (int kk = 0; kk < 4; kk++) {
                f32x4 z = {0.f, 0.f, 0.f, 0.f};
                f32x4 S = __builtin_amdgcn_mfma_f32_16x16x32_bf16(qf, kf[c * 4 + kk], z, 0, 0, 0);
                p[kk][0] = exp2f(S[0]); p[kk][1] = exp2f(S[1]);
                p[kk][2] = exp2f(S[2]); p[kk][3] = exp2f(S[3]);
                l0 += p[kk][0]; l1 += p[kk][1]; l2 += p[kk][2]; l3 += p[kk][3];
            }
            #pragma unroll
            for (int r = 0; r < 4; r++) {
                unsigned w0 = (unsigned)(unsigned short)f2bf(p[0][r])
                            | ((unsigned)(unsigned short)f2bf(p[1][r]) << 16);
                unsigned w1 = (unsigned)(unsigned short)f2bf(p[2][r])
                            | ((unsigned)(unsigned short)f2bf(p[3][r]) << 16);
                *(uint2*)&pbuf[(4 * quad + r) * 64 + col * 4] = make_uint2(w0, w1);
            }
            #pragma unroll
            for (int half = 0; half < 2; half++) {
                int tb = c * 64 + half * 32;
                bf16x8 pf = *(const bf16x8*)&pbuf[col * 64 + half * 32 + quad * 8];
                bf16x8 vf = *(const bf16x8*)&Vt[col][tb + quad * 8];
                O = __builtin_amdgcn_mfma_f32_16x16x32_bf16(pf, vf, O, 0, 0, 0);
            }
        }

        float l[4] = {l0, l1, l2, l3};
        #pragma unroll
        for (int r = 0; r < 4; r++) {
            #pragma unroll
            for (int off = 1; off < 16; off <<= 1) l[r] += __shfl_xor(l[r], off, 64);
            float inv = __builtin_amdgcn_rcpf(l[r]);
            int q = q0 + 4 * quad + r;
            ctx[(size_t)(q * BB + b) * DD + h * 16 + col] = (ushort)f2bf(O[r] * inv);
        }
    }
}

// ---------------- Kernel 5: fused mean-pool + head (outln fp32) -------------
__global__ __launch_bounds__(256) void k_poolfinal(const float* __restrict__ outln,
                                                   const float* __restrict__ Wf,
                                                   const float* __restrict__ bfv,
                                                   float* __restrict__ out) {
    int b = blockIdx.x;
    int tid = threadIdx.x;
    __shared__ float part[256];
    __shared__ float pooled[128];
    int d = tid & 127, half = tid >> 7;
    float s = 0.f;
    int s0 = half * 256;
    #pragma unroll 8
    for (int si = s0; si < s0 + 256; si++)
        s += outln[(size_t)(si * BB + b) * DD + d];
    part[tid] = s;
    __syncthreads();
    if (tid < 128) pooled[tid] = (part[tid] + part[tid + 128]) * (1.0f / SS);
    __syncthreads();
    if (tid < 32) {
        const float* wr = Wf + tid * DD;
        float acc = bfv[tid];
        #pragma unroll
        for (int k = 0; k < DD; k += 4) {
            float4 wv = *(const float4*)(wr + k);
            acc += pooled[k] * wv.x + pooled[k + 1] * wv.y
                 + pooled[k + 2] * wv.z + pooled[k + 3] * wv.w;
        }
        out[b * 32 + tid] = fast_tanh(acc);
    }
}

extern "C" void kernel_launch(void* const* d_in, const int* in_sizes, int n_in,
                              void* d_out, int out_size, void* d_ws, size_t ws_size,
                              hipStream_t stream) {
    const float* x    = (const float*)d_in[0];
    const float* W_ih = (const float*)d_in[1];
    const float* b_ih = (const float*)d_in[2];
    const float* W_hh = (const float*)d_in[3];
    const float* b_hh = (const float*)d_in[4];
    const float* Wp   = (const float*)d_in[5];
    const float* bp   = (const float*)d_in[6];
    const float* Wqkv = (const float*)d_in[7];
    const float* bqkv = (const float*)d_in[8];
    const float* Wo   = (const float*)d_in[9];
    const float* bo   = (const float*)d_in[10];
    const float* g1   = (const float*)d_in[11];
    const float* be1  = (const float*)d_in[12];
    const float* W1   = (const float*)d_in[13];
    const float* b1   = (const float*)d_in[14];
    const float* W2   = (const float*)d_in[15];
    const float* b2   = (const float*)d_in[16];
    const float* g2   = (const float*)d_in[17];
    const float* be2  = (const float*)d_in[18];
    const float* gn   = (const float*)d_in[19];
    const float* bn   = (const float*)d_in[20];
    const float* Wf   = (const float*)d_in[21];
    const float* bf   = (const float*)d_in[22];
    float* out = (float*)d_out;
    char* wsb = (char*)d_ws;

    // workspace layout (bytes); bf16 intermediates. ~96.7 MB.
    float*  xw    = (float*)(wsb);                      // 8MB   [xw .. rnn]
    float*  hsf   = (float*)(wsb + (8u << 20));         // 8MB   [rnn .. projqkv]
    ushort* projb = (ushort*)(wsb + (16u << 20));       // 8MB   [projqkv .. end]
    ushort* qkvb  = (ushort*)(wsb + (24u << 20));       // 24MB  [projqkv .. attn]
    ushort* ctxb  = (ushort*)(wsb + (48u << 20));       // 8MB   [attn .. Wo]
    ushort* x1b   = (ushort*)(wsb + (56u << 20));       // 8MB   [Wo .. ff2]
    ushort* ff1b  = (ushort*)(wsb + (64u << 20));       // 16MB  [ff1 .. ff2]
    float*  outln = (float*)(wsb + (80u << 20));        // 16MB  [ff2 .. pool]
    ushort* wbf   = (ushort*)(wsb + (96u << 20));       // weights bf16
    ushort* Wp_bf   = wbf;
    ushort* Wo_bf   = wbf + 57344;
    ushort* W1_bf   = wbf + 73728;
    ushort* W2_bf   = wbf + 106496;
    ushort* Wq2_bf  = wbf + 139264;                     // folded Wqkv.Wp (384x64)
    float*  bq2     = (float*)(wbf + 163840);           // folded bias (384)

    k_xw_wcvt<<<8832, 256, 0, stream>>>(x, W_ih, b_ih, b_hh, xw,
                                        Wp, Wqkv, Wo, W1, W2, bp, bqkv,
                                        wbf, Wq2_bf, bq2);
    k_rnn<<<64, 64, 0, stream>>>(xw, W_hh, hsf);
    // proj (512 blocks) + qkv (1536 blocks, folded K=64) in ONE dispatch
    k_projqkv<<<2048, 256, 0, stream>>>(hsf, Wp_bf, bp, projb, Wq2_bf, bq2, qkvb);
    k_attn<<<512, 256, 0, stream>>>(qkvb, ctxb);
    // x1 = LN1(proj + ctx@Wo^T + bo)
    k_gemm_ln_m64b<128, 1, true><<<512, 256, 0, stream>>>(ctxb, Wo_bf, bo, projb, g1, be1,
                                                          nullptr, nullptr, nullptr, x1b);
    k_gemm_m64b<128, true, true><<<dim3(512, 2), 256, 0, stream>>>(x1b, W1_bf, b1, ff1b, 256);
    // outln = LN3( LN2(x1 + ff1@W2^T + b2) + proj )   (fp32 out for pool)
    k_gemm_ln_m64b<256, 2, false><<<512, 256, 0, stream>>>(ff1b, W2_bf, b2, x1b, g2, be2,
                                                           projb, gn, bn, outln);
    k_poolfinal<<<64, 256, 0, stream>>>(outln, Wf, bf, out);
}

// Round 19
// 384.593 us; speedup vs baseline: 1.2819x; 1.0315x over previous
//
#include <hip/hip_runtime.h>
#include <hip/hip_bf16.h>

#define BB 64
#define SS 512
#define II 32
#define HH 64
#define DD 128
#define FF 256
#define NHEAD 8
#define HDIM 16
#define NTOK (SS*BB)   // 32768

typedef short bf16x8 __attribute__((ext_vector_type(8)));
typedef float f32x4  __attribute__((ext_vector_type(4)));

__device__ __forceinline__ float fast_tanh(float x) {
    float ax = fabsf(x);
    float e = __expf(-2.0f * ax);
    float r = (1.0f - e) * __builtin_amdgcn_rcpf(1.0f + e);
    return copysignf(r, x);
}

__device__ __forceinline__ float bcast(float v, int lane) {
    return __int_as_float(__builtin_amdgcn_readlane(__float_as_int(v), lane));
}

// fp32 -> bf16 bits, round-to-nearest-even
__device__ __forceinline__ short f2bf(float x) {
    unsigned u = __float_as_uint(x);
    return (short)((u + 0x7FFFu + ((u >> 16) & 1u)) >> 16);
}
__device__ __forceinline__ float bf2f(ushort u) {
    return __uint_as_float((unsigned)u << 16);
}

// ---- Kernel 1: xw (bid<8192) + weight-cvt (bid>=8192) ----------------------
// Wqkv K-rows pre-scaled by 0.25*log2e (attention reads raw). W1 slot holds
// W1 with K PERMUTED (p -> d(p)=(p&7)*16+(p>>3)); W2 slot holds W2 with K
// permuted per 128-half. These match the fused tail kernel's internal
// X1/F1 LDS layouts (C->A handoff becomes one b128 write per row).
__global__ __launch_bounds__(256) void k_xw_wcvt(const float* __restrict__ x,
                                                 const float* __restrict__ W_ih,
                                                 const float* __restrict__ b_ih,
                                                 const float* __restrict__ b_hh,
                                                 float* __restrict__ xw,
                                                 const float* __restrict__ Wp,
                                                 const float* __restrict__ Wqkv,
                                                 const float* __restrict__ Wo,
                                                 const float* __restrict__ W1,
                                                 const float* __restrict__ W2,
                                                 ushort* __restrict__ wout) {
    if (blockIdx.x >= 8192) {
        int i = (blockIdx.x - 8192) * 256 + threadIdx.x;   // 139264 total
        float v;
        if (i < 8192) v = Wp[i];
        else if (i < 57344) {
            int e = i - 8192;
            v = Wqkv[e];
            int row = e >> 7;
            if (row >= 128 && row < 256) v *= 0.36067376f;  // 0.25 * log2(e)
        }
        else if (i < 73728) v = Wo[i - 57344];
        else if (i < 106496) {               // W1, K-permuted
            int e = i - 73728, n = e >> 7, p = e & 127;
            v = W1[n * 128 + (p & 7) * 16 + (p >> 3)];
        }
        else {                                // W2, K-permuted per 128-half
            int e = i - 106496, n = e >> 8, kp = e & 255;
            int nc = kp >> 7, pl = kp & 127;
            v = W2[n * 256 + nc * 128 + (pl & 7) * 16 + (pl >> 3)];
        }
        wout[i] = (ushort)f2bf(v);
        return;
    }
    int idx = blockIdx.x * 256 + threadIdx.x;  // over S*B*H = 2M
    int j  = idx & (HH - 1);
    int sb = idx >> 6;          // s*B + b
    int s  = sb >> 6;           // / B
    int b  = sb & (BB - 1);
    const float* xr = x + (b * SS + s) * II;
    const float* wr = W_ih + j * II;
    float acc = b_ih[j] + b_hh[j];
    #pragma unroll
    for (int k = 0; k < II; k += 4) {
        float4 xv = *(const float4*)(xr + k);
        float4 wv = *(const float4*)(wr + k);
        acc += xv.x * wv.x + xv.y * wv.y + xv.z * wv.z + xv.w * wv.w;
    }
    xw[idx] = acc;
}

// ---------------- Kernel 2: RNN recurrence -- FROZEN (134.5us x6) -----------
__global__ __launch_bounds__(64, 1) void k_rnn(const float* __restrict__ xw,
                                               const float* __restrict__ W_hh,
                                               float* __restrict__ hs) {
    int b = blockIdx.x;
    int j = threadIdx.x;
    float w[HH];
    #pragma unroll
    for (int k = 0; k < HH; k++) w[k] = W_hh[j * HH + k];

    float hv = 0.0f;
    float xv0 = xw[(0 * BB + b) * HH + j];
    float xv1 = xw[(1 * BB + b) * HH + j];
    for (int t = 0; t < SS; t++) {
        int tn = (t < SS - 2) ? t + 2 : t;
        float xnext = xw[(tn * BB + b) * HH + j];  // prefetch depth 2
        float a0 = xv0, a1 = 0.f, a2 = 0.f, a3 = 0.f;
        #pragma unroll
        for (int k = 0; k < HH; k += 4) {
            a0 = fmaf(w[k + 0], bcast(hv, k + 0), a0);
            a1 = fmaf(w[k + 1], bcast(hv, k + 1), a1);
            a2 = fmaf(w[k + 2], bcast(hv, k + 2), a2);
            a3 = fmaf(w[k + 3], bcast(hv, k + 3), a3);
        }
        hv = fast_tanh((a0 + a1) + (a2 + a3));
        hs[(t * BB + b) * HH + j] = hv;   // fire-and-forget
        xv0 = xv1;
        xv1 = xnext;
    }
}

// ------ Kernel 3a: proj GEMM, fp32 A converted in staging, bf16 W (R16) -----
template<int K, bool RELU>
__global__ __launch_bounds__(256) void k_gemm_m64fa(const float* __restrict__ A,
                                                    const ushort* __restrict__ W,
                                                    const float* __restrict__ bias,
                                                    ushort* __restrict__ C, int N) {
    __shared__ short As[64 * 40];
    __shared__ short Ws[128 * 40];
    int tid = threadIdx.x;
    int wid = tid >> 6, lane = tid & 63;
    int col = lane & 15, quad = lane >> 4;
    int rowBase = blockIdx.x * 64, colBase = blockIdx.y * 128;

    f32x4 acc[8];
    #pragma unroll
    for (int nt = 0; nt < 8; nt++) {
        float bv = bias[colBase + nt * 16 + col];
        acc[nt][0] = bv; acc[nt][1] = bv; acc[nt][2] = bv; acc[nt][3] = bv;
    }

    int arow = tid >> 2, akc = (tid & 3) * 8;
    int wrow = tid >> 1, wkc = (tid & 1) * 16;

    for (int kb = 0; kb < K; kb += 32) {
        {
            const float4* ap = (const float4*)(A + (size_t)(rowBase + arow) * K + kb + akc);
            float4 v0 = ap[0], v1 = ap[1];
            short t0[8];
            t0[0]=f2bf(v0.x); t0[1]=f2bf(v0.y); t0[2]=f2bf(v0.z); t0[3]=f2bf(v0.w);
            t0[4]=f2bf(v1.x); t0[5]=f2bf(v1.y); t0[6]=f2bf(v1.z); t0[7]=f2bf(v1.w);
            *(int4*)&As[arow * 40 + akc] = *(int4*)t0;
        }
        {
            const int4* wp = (const int4*)(W + (size_t)(colBase + wrow) * K + kb + wkc);
            *(int4*)&Ws[wrow * 40 + wkc]     = wp[0];
            *(int4*)&Ws[wrow * 40 + wkc + 8] = wp[1];
        }
        __syncthreads();

        bf16x8 af = *(const bf16x8*)&As[(wid * 16 + col) * 40 + quad * 8];
        bf16x8 wf[8];
        #pragma unroll
        for (int nt = 0; nt < 8; nt++)
            wf[nt] = *(const bf16x8*)&Ws[(nt * 16 + col) * 40 + quad * 8];
        #pragma unroll
        for (int nt = 0; nt < 8; nt++)
            acc[nt] = __builtin_amdgcn_mfma_f32_16x16x32_bf16(af, wf[nt], acc[nt], 0, 0, 0);
        __syncthreads();
    }

    #pragma unroll
    for (int r = 0; r < 4; r++) {
        int m = rowBase + wid * 16 + quad * 4 + r;
        #pragma unroll
        for (int nt = 0; nt < 8; nt++) {
            float v = acc[nt][r];
            if (RELU) v = fmaxf(v, 0.f);
            C[(size_t)m * N + colBase + nt * 16 + col] = (ushort)f2bf(v);
        }
    }
}

// ------ Kernel 3b: bf16-in GEMM, M=64 x N=128 tile (R16 form) ---------------
template<int K, bool RELU, bool OUTBF>
__global__ __launch_bounds__(256) void k_gemm_m64b(const ushort* __restrict__ A,
                                                   const ushort* __restrict__ W,
                                                   const float* __restrict__ bias,
                                                   void* __restrict__ Cv, int N) {
    __shared__ short As[64 * 40];
    __shared__ short Ws[128 * 40];
    int tid = threadIdx.x;
    int wid = tid >> 6, lane = tid & 63;
    int col = lane & 15, quad = lane >> 4;
    int rowBase = blockIdx.x * 64, colBase = blockIdx.y * 128;

    f32x4 acc[8];
    #pragma unroll
    for (int nt = 0; nt < 8; nt++) {
        float bv = bias[colBase + nt * 16 + col];
        acc[nt][0] = bv; acc[nt][1] = bv; acc[nt][2] = bv; acc[nt][3] = bv;
    }

    int arow = tid >> 2, akc = (tid & 3) * 8;
    int wrow = tid >> 1, wkc = (tid & 1) * 16;

    for (int kb = 0; kb < K; kb += 32) {
        *(int4*)&As[arow * 40 + akc] =
            *(const int4*)(A + (size_t)(rowBase + arow) * K + kb + akc);
        {
            const int4* wp = (const int4*)(W + (size_t)(colBase + wrow) * K + kb + wkc);
            *(int4*)&Ws[wrow * 40 + wkc]     = wp[0];
            *(int4*)&Ws[wrow * 40 + wkc + 8] = wp[1];
        }
        __syncthreads();

        bf16x8 af = *(const bf16x8*)&As[(wid * 16 + col) * 40 + quad * 8];
        bf16x8 wf[8];
        #pragma unroll
        for (int nt = 0; nt < 8; nt++)
            wf[nt] = *(const bf16x8*)&Ws[(nt * 16 + col) * 40 + quad * 8];
        #pragma unroll
        for (int nt = 0; nt < 8; nt++)
            acc[nt] = __builtin_amdgcn_mfma_f32_16x16x32_bf16(af, wf[nt], acc[nt], 0, 0, 0);
        __syncthreads();
    }

    #pragma unroll
    for (int r = 0; r < 4; r++) {
        int m = rowBase + wid * 16 + quad * 4 + r;
        #pragma unroll
        for (int nt = 0; nt < 8; nt++) {
            float v = acc[nt][r];
            if (RELU) v = fmaxf(v, 0.f);
            if (OUTBF)
                ((ushort*)Cv)[(size_t)m * N + colBase + nt * 16 + col] = (ushort)f2bf(v);
            else
                ((float*)Cv)[(size_t)m * N + colBase + nt * 16 + col] = v;
        }
    }
}

// ------ Kernel 4: fused tail  x1=LN1(proj+ctx@Wo^T+bo); ff1=relu(x1@W1^T+b1);
//        outln=LN3(LN2(x1+ff1@W2^T+b2)+proj).  x1/ff1 NEVER touch global
//        (56 MB HBM saved vs R16). Internal LDS layouts use permuted column
//        order p=col*8+nt so each C->A handoff is one b128 write per row;
//        W1/W2 arrive with K pre-permuted to match (converter). Interfaces
//        (proj/ctx/outln/biases/gammas) all normal order -> values bit-
//        identical to R16 (absmax must stay 1.953e-3).
// LDS arena 60KB: F1@0 (64x264, overlays phase-1 As), X1@16896 (64x136),
// Ws@25600 (128x40). 2 blocks/CU.
__global__ __launch_bounds__(256) void k_tail(const ushort* __restrict__ ctx,
                                              const ushort* __restrict__ Wo,
                                              const float* __restrict__ bo,
                                              const ushort* __restrict__ projb,
                                              const float* __restrict__ g1v,
                                              const float* __restrict__ be1v,
                                              const ushort* __restrict__ W1p,
                                              const float* __restrict__ b1v,
                                              const ushort* __restrict__ W2p,
                                              const float* __restrict__ b2v,
                                              const float* __restrict__ g2v,
                                              const float* __restrict__ be2v,
                                              const float* __restrict__ gnv,
                                              const float* __restrict__ bnv,
                                              float* __restrict__ outln) {
    __shared__ short smem[30720];
    short* F1 = smem;              // 64*264 (phase 3+), overlays As (phase 1)
    short* As = smem;              // 64*40 (phase 1 only)
    short* X1 = smem + 16896;      // 64*136
    short* Ws = smem + 25600;      // 128*40
    int tid = threadIdx.x;
    int wid = tid >> 6, lane = tid & 63;
    int col = lane & 15, quad = lane >> 4;
    int rowBase = blockIdx.x * 64;
    int arow = tid >> 2, akc = (tid & 3) * 8;
    int wrow = tid >> 1, wkc = (tid & 1) * 16;

    // ---- phase 1: acc = ctx @ Wo^T + bo  (K=128) ----
    f32x4 acc[8];
    #pragma unroll
    for (int nt = 0; nt < 8; nt++) {
        float bv = bo[nt * 16 + col];
        acc[nt][0] = bv; acc[nt][1] = bv; acc[nt][2] = bv; acc[nt][3] = bv;
    }
    for (int kb = 0; kb < 128; kb += 32) {
        *(int4*)&As[arow * 40 + akc] =
            *(const int4*)(ctx + (size_t)(rowBase + arow) * 128 + kb + akc);
        {
            const int4* wp = (const int4*)(Wo + (size_t)wrow * 128 + kb + wkc);
            *(int4*)&Ws[wrow * 40 + wkc]     = wp[0];
            *(int4*)&Ws[wrow * 40 + wkc + 8] = wp[1];
        }
        __syncthreads();
        bf16x8 af = *(const bf16x8*)&As[(wid * 16 + col) * 40 + quad * 8];
        #pragma unroll
        for (int nt = 0; nt < 8; nt++) {
            bf16x8 wf = *(const bf16x8*)&Ws[(nt * 16 + col) * 40 + quad * 8];
            acc[nt] = __builtin_amdgcn_mfma_f32_16x16x32_bf16(af, wf, acc[nt], 0, 0, 0);
        }
        __syncthreads();
    }

    // ---- LN1 (+proj residual) -> X1 in LDS (permuted cols, b128/row) ----
    float ga[8], ba[8];
    #pragma unroll
    for (int nt = 0; nt < 8; nt++) { ga[nt] = g1v[nt*16+col]; ba[nt] = be1v[nt*16+col]; }
    #pragma unroll
    for (int r = 0; r < 4; r++) {
        int ml = wid * 16 + quad * 4 + r;
        const ushort* rr1 = projb + (size_t)(rowBase + ml) * DD;
        float v[8];
        float s = 0.f;
        #pragma unroll
        for (int nt = 0; nt < 8; nt++) { v[nt] = acc[nt][r] + bf2f(rr1[nt*16+col]); s += v[nt]; }
        #pragma unroll
        for (int off = 1; off < 16; off <<= 1) s += __shfl_xor(s, off, 64);
        float mu = s * (1.0f / 128.0f);
        float vs = 0.f;
        #pragma unroll
        for (int nt = 0; nt < 8; nt++) { v[nt] -= mu; vs += v[nt] * v[nt]; }
        #pragma unroll
        for (int off = 1; off < 16; off <<= 1) vs += __shfl_xor(vs, off, 64);
        float rstd = rsqrtf(vs * (1.0f / 128.0f) + 1e-5f);
        short pk[8];
        #pragma unroll
        for (int nt = 0; nt < 8; nt++) pk[nt] = f2bf(v[nt] * rstd * ga[nt] + ba[nt]);
        *(int4*)&X1[ml * 136 + col * 8] = *(int4*)pk;   // X1[m][p=col*8+nt]
    }
    __syncthreads();

    // ---- phase 3: ff1 = relu(X1 @ W1p^T + b1), halves of 128 cols ----
    #pragma unroll 1
    for (int nc = 0; nc < 2; nc++) {
        f32x4 acc2[8];
        #pragma unroll
        for (int nt = 0; nt < 8; nt++) {
            float bv = b1v[nc * 128 + nt * 16 + col];
            acc2[nt][0] = bv; acc2[nt][1] = bv; acc2[nt][2] = bv; acc2[nt][3] = bv;
        }
        for (int kb = 0; kb < 128; kb += 32) {
            const int4* wp = (const int4*)(W1p + (size_t)(nc * 128 + wrow) * 128 + kb + wkc);
            *(int4*)&Ws[wrow * 40 + wkc]     = wp[0];
            *(int4*)&Ws[wrow * 40 + wkc + 8] = wp[1];
            __syncthreads();
            bf16x8 af = *(const bf16x8*)&X1[(wid * 16 + col) * 136 + kb + quad * 8];
            #pragma unroll
            for (int nt = 0; nt < 8; nt++) {
                bf16x8 wf = *(const bf16x8*)&Ws[(nt * 16 + col) * 40 + quad * 8];
                acc2[nt] = __builtin_amdgcn_mfma_f32_16x16x32_bf16(af, wf, acc2[nt], 0, 0, 0);
            }
            __syncthreads();
        }
        #pragma unroll
        for (int r = 0; r < 4; r++) {
            int ml = wid * 16 + quad * 4 + r;
            short pk[8];
            #pragma unroll
            for (int nt = 0; nt < 8; nt++) pk[nt] = f2bf(fmaxf(acc2[nt][r], 0.f));
            *(int4*)&F1[ml * 264 + nc * 128 + col * 8] = *(int4*)pk;
        }
    }
    __syncthreads();

    // ---- phase 4: ff2 = F1 @ W2p^T + b2  (K=256) ----
    f32x4 acc3[8];
    #pragma unroll
    for (int nt = 0; nt < 8; nt++) {
        float bv = b2v[nt * 16 + col];
        acc3[nt][0] = bv; acc3[nt][1] = bv; acc3[nt][2] = bv; acc3[nt][3] = bv;
    }
    for (int kb = 0; kb < 256; kb += 32) {
        const int4* wp = (const int4*)(W2p + (size_t)wrow * 256 + kb + wkc);
        *(int4*)&Ws[wrow * 40 + wkc]     = wp[0];
        *(int4*)&Ws[wrow * 40 + wkc + 8] = wp[1];
        __syncthreads();
        bf16x8 af = *(const bf16x8*)&F1[(wid * 16 + col) * 264 + kb + quad * 8];
        #pragma unroll
        for (int nt = 0; nt < 8; nt++) {
            bf16x8 wf = *(const bf16x8*)&Ws[(nt * 16 + col) * 40 + quad * 8];
            acc3[nt] = __builtin_amdgcn_mfma_f32_16x16x32_bf16(af, wf, acc3[nt], 0, 0, 0);
        }
        __syncthreads();
    }

    // ---- LN2 (res=X1 from LDS) then LN3 (res=proj) -> outln fp32 ----
    float g2a[8], b2a[8], gna[8], bna[8];
    #pragma unroll
    for (int nt = 0; nt < 8; nt++) {
        g2a[nt] = g2v[nt*16+col]; b2a[nt] = be2v[nt*16+col];
        gna[nt] = gnv[nt*16+col]; bna[nt] = bnv[nt*16+col];
    }
    #pragma unroll
    for (int r = 0; r < 4; r++) {
        int ml = wid * 16 + quad * 4 + r;
        bf16x8 x1v = *(const bf16x8*)&X1[ml * 136 + col * 8];  // [p=col*8+nt]
        float v[8];
        float s = 0.f;
        #pragma unroll
        for (int nt = 0; nt < 8; nt++) {
            v[nt] = acc3[nt][r] + bf2f((ushort)x1v[nt]);
            s += v[nt];
        }
        #pragma unroll
        for (int off = 1; off < 16; off <<= 1) s += __shfl_xor(s, off, 64);
        float mu = s * (1.0f / 128.0f);
        float vs = 0.f;
        #pragma unroll
        for (int nt = 0; nt < 8; nt++) { v[nt] -= mu; vs += v[nt] * v[nt]; }
        #pragma unroll
        for (int off = 1; off < 16; off <<= 1) vs += __shfl_xor(vs, off, 64);
        float rstd = rsqrtf(vs * (1.0f / 128.0f) + 1e-5f);
        #pragma unroll
        for (int nt = 0; nt < 8; nt++) v[nt] = v[nt] * rstd * g2a[nt] + b2a[nt];

        const ushort* rr2 = projb + (size_t)(rowBase + ml) * DD;
        float s2 = 0.f;
        #pragma unroll
        for (int nt = 0; nt < 8; nt++) { v[nt] += bf2f(rr2[nt*16+col]); s2 += v[nt]; }
        #pragma unroll
        for (int off = 1; off < 16; off <<= 1) s2 += __shfl_xor(s2, off, 64);
        float mu2 = s2 * (1.0f / 128.0f);
        float vs2 = 0.f;
        #pragma unroll
        for (int nt = 0; nt < 8; nt++) { v[nt] -= mu2; vs2 += v[nt] * v[nt]; }
        #pragma unroll
        for (int off = 1; off < 16; off <<= 1) vs2 += __shfl_xor(vs2, off, 64);
        float rstd2 = rsqrtf(vs2 * (1.0f / 128.0f) + 1e-5f);
        float* orow = outln + (size_t)(rowBase + ml) * DD;
        #pragma unroll
        for (int nt = 0; nt < 8; nt++)
            orow[nt * 16 + col] = v[nt] * rstd2 * gna[nt] + bna[nt];
    }
}

// ---------------- Kernel 5: MFMA flash attention, bf16 qkv (R16 form) -------
__global__ __launch_bounds__(256, 2) void k_attn(const ushort* __restrict__ qkv,
                                                 ushort* __restrict__ ctx) {
    int bh = blockIdx.x;
    int b = bh >> 3, h = bh & 7;
    __shared__ short Vt[HDIM][SS];
    __shared__ short Pb[4][2][16 * 64];
    int tid = threadIdx.x;

    for (int t = tid; t < SS; t += 256) {
        const ushort* base = qkv + (size_t)(t * BB + b) * 384 + 256 + h * 16;
        int4 va = *(const int4*)base;
        int4 vb = *(const int4*)(base + 8);
        const ushort* pa = (const ushort*)&va;
        const ushort* pb = (const ushort*)&vb;
        int u = t & 63;
        int pos = (t & ~63) | (((u & 15) << 2) | (u >> 4));
        #pragma unroll
        for (int d = 0; d < 8; d++) {
            Vt[d][pos]     = pa[d];
            Vt[d + 8][pos] = pb[d];
        }
    }
    __syncthreads();

    int wid = tid >> 6, lane = tid & 63;
    int col = lane & 15, quad = lane >> 4;

    bf16x8 kf[32];
    #pragma unroll
    for (int kt = 0; kt < 32; kt++) {
        bf16x8 f = (bf16x8)(short)0;
        if (quad < 2)
            f = *(const bf16x8*)(qkv + (size_t)((kt * 16 + col) * BB + b) * 384
                                 + 128 + h * 16 + quad * 8);
        kf[kt] = f;
    }

    for (int sub = 0; sub < 8; sub++) {
        int q0 = wid * 128 + sub * 16;

        bf16x8 qf = (bf16x8)(short)0;
        if (quad < 2)
            qf = *(const bf16x8*)(qkv + (size_t)((q0 + col) * BB + b) * 384
                                  + h * 16 + quad * 8);

        float l0 = 0.f, l1 = 0.f, l2 = 0.f, l3 = 0.f;
        f32x4 O = {0.f, 0.f, 0.f, 0.f};
        #pragma unroll
        for (int c = 0; c < 8; c++) {
            short* pbuf = &Pb[wid][c & 1][0];
            float p[4][4];
            #pragma unroll
            for (int kk = 0; kk < 4; kk++) {
                f32x4 z = {0.f, 0.f, 0.f, 0.f};
                f32x4 S = __builtin_amdgcn_mfma_f32_16x16x32_bf16(qf, kf[c * 4 + kk], z, 0, 0, 0);
                p[kk][0] = exp2f(S[0]); p[kk][1] = exp2f(S[1]);
                p[kk][2] = exp2f(S[2]); p[kk][3] = exp2f(S[3]);
                l0 += p[kk][0]; l1 += p[kk][1]; l2 += p[kk][2]; l3 += p[kk][3];
            }
            #pragma unroll
            for (int r = 0; r < 4; r++) {
                unsigned w0 = (unsigned)(unsigned short)f2bf(p[0][r])
                            | ((unsigned)(unsigned short)f2bf(p[1][r]) << 16);
                unsigned w1 = (unsigned)(unsigned short)f2bf(p[2][r])
                            | ((unsigned)(unsigned short)f2bf(p[3][r]) << 16);
                *(uint2*)&pbuf[(4 * quad + r) * 64 + col * 4] = make_uint2(w0, w1);
            }
            #pragma unroll
            for (int half = 0; half < 2; half++) {
                int tb = c * 64 + half * 32;
                bf16x8 pf = *(const bf16x8*)&pbuf[col * 64 + half * 32 + quad * 8];
                bf16x8 vf = *(const bf16x8*)&Vt[col][tb + quad * 8];
                O = __builtin_amdgcn_mfma_f32_16x16x32_bf16(pf, vf, O, 0, 0, 0);
            }
        }

        float l[4] = {l0, l1, l2, l3};
        #pragma unroll
        for (int r = 0; r < 4; r++) {
            #pragma unroll
            for (int off = 1; off < 16; off <<= 1) l[r] += __shfl_xor(l[r], off, 64);
            float inv = __builtin_amdgcn_rcpf(l[r]);
            int q = q0 + 4 * quad + r;
            ctx[(size_t)(q * BB + b) * DD + h * 16 + col] = (ushort)f2bf(O[r] * inv);
        }
    }
}

// ---------------- Kernel 6: fused mean-pool + head (outln fp32) -------------
__global__ __launch_bounds__(256) void k_poolfinal(const float* __restrict__ outln,
                                                   const float* __restrict__ Wf,
                                                   const float* __restrict__ bfv,
                                                   float* __restrict__ out) {
    int b = blockIdx.x;
    int tid = threadIdx.x;
    __shared__ float part[256];
    __shared__ float pooled[128];
    int d = tid & 127, half = tid >> 7;
    float s = 0.f;
    int s0 = half * 256;
    #pragma unroll 8
    for (int si = s0; si < s0 + 256; si++)
        s += outln[(size_t)(si * BB + b) * DD + d];
    part[tid] = s;
    __syncthreads();
    if (tid < 128) pooled[tid] = (part[tid] + part[tid + 128]) * (1.0f / SS);
    __syncthreads();
    if (tid < 32) {
        const float* wr = Wf + tid * DD;
        float acc = bfv[tid];
        #pragma unroll
        for (int k = 0; k < DD; k += 4) {
            float4 wv = *(const float4*)(wr + k);
            acc += pooled[k] * wv.x + pooled[k + 1] * wv.y
                 + pooled[k + 2] * wv.z + pooled[k + 3] * wv.w;
        }
        out[b * 32 + tid] = fast_tanh(acc);
    }
}

extern "C" void kernel_launch(void* const* d_in, const int* in_sizes, int n_in,
                              void* d_out, int out_size, void* d_ws, size_t ws_size,
                              hipStream_t stream) {
    const float* x    = (const float*)d_in[0];
    const float* W_ih = (const float*)d_in[1];
    const float* b_ih = (const float*)d_in[2];
    const float* W_hh = (const float*)d_in[3];
    const float* b_hh = (const float*)d_in[4];
    const float* Wp   = (const float*)d_in[5];
    const float* bp   = (const float*)d_in[6];
    const float* Wqkv = (const float*)d_in[7];
    const float* bqkv = (const float*)d_in[8];
    const float* Wo   = (const float*)d_in[9];
    const float* bo   = (const float*)d_in[10];
    const float* g1   = (const float*)d_in[11];
    const float* be1  = (const float*)d_in[12];
    const float* W1   = (const float*)d_in[13];
    const float* b1   = (const float*)d_in[14];
    const float* W2   = (const float*)d_in[15];
    const float* b2   = (const float*)d_in[16];
    const float* g2   = (const float*)d_in[17];
    const float* be2  = (const float*)d_in[18];
    const float* gn   = (const float*)d_in[19];
    const float* bn   = (const float*)d_in[20];
    const float* Wf   = (const float*)d_in[21];
    const float* bf   = (const float*)d_in[22];
    float* out = (float*)d_out;
    char* wsb = (char*)d_ws;

    // workspace layout (bytes); bf16 intermediates.
    float*  xw    = (float*)(wsb);                      // 8MB   [xw .. rnn]
    float*  hsf   = (float*)(wsb + (8u << 20));         // 8MB   [rnn .. proj]
    ushort* projb = (ushort*)(wsb + (16u << 20));       // 8MB   [proj .. tail]
    ushort* qkvb  = (ushort*)(wsb + (24u << 20));       // 24MB  [qkv .. attn]
    ushort* ctxb  = (ushort*)(wsb + (48u << 20));       // 8MB   [attn .. tail]
    float*  outln = (float*)(wsb + (56u << 20));        // 16MB  [tail .. pool]
    ushort* wbf   = (ushort*)(wsb + (80u << 20));       // weights bf16
    ushort* Wp_bf   = wbf;
    ushort* Wqkv_bf = wbf + 8192;
    ushort* Wo_bf   = wbf + 57344;
    ushort* W1p_bf  = wbf + 73728;   // K-permuted
    ushort* W2p_bf  = wbf + 106496;  // K-permuted

    k_xw_wcvt<<<8736, 256, 0, stream>>>(x, W_ih, b_ih, b_hh, xw,
                                        Wp, Wqkv, Wo, W1, W2, wbf);
    k_rnn<<<64, 64, 0, stream>>>(xw, W_hh, hsf);
    k_gemm_m64fa<64, false><<<dim3(512, 1), 256, 0, stream>>>(hsf, Wp_bf, bp, projb, 128);
    k_gemm_m64b<128, false, true><<<dim3(512, 3), 256, 0, stream>>>(projb, Wqkv_bf, bqkv,
                                                                    qkvb, 384);
    k_attn<<<512, 256, 0, stream>>>(qkvb, ctxb);
    // fused: LN1(Wo) -> ff1 -> ff2 -> LN2 -> LN3, x1/ff1 LDS-resident
    k_tail<<<512, 256, 0, stream>>>(ctxb, Wo_bf, bo, projb, g1, be1,
                                    W1p_bf, b1, W2p_bf, b2, g2, be2, gn, bn, outln);
    k_poolfinal<<<64, 256, 0, stream>>>(outln, Wf, bf, out);
}